// Round 2
// baseline (4989.304 us; speedup 1.0000x reference)
//
#include <hip/hip_runtime.h>
#include <math.h>

// MACE layer, f32. Round 8: R7 split path worked (7154->3543us) but the mix
// buffer (1.34GB) didn't fit ws -> ~16 slices x (k_mlp+k_tp), each a tiny
// 512-block grid: slicing/launch tax dominated (no dispatch >212us, total
// 3543us). Fix: fuse MLP+TP into ONE edge-parallel kernel with everything
// that made the split fast: wave-private in-place MLP (0 barriers), w4 from
// L2 (no 32KB stage), block = 64 receiver-sorted edges (perfect balance,
// E = 8192*64 exact), 8-node LDS window + atomic flush to zeroed agg.
// LDS 35.5KB -> 4 blocks/CU; 3 barriers/block; no mix traffic at all.
// K1: node pre   Ksort: hist/scan/permute   K2: fused edge   K3: epilogue

#define N_NODES 32768
#define N_EDGES 524288
#define FCH 128
#define NBASIS 8
#define HDIM 64
#define CE 64      // edges per block in K2 (N_EDGES = 8192 * CE exactly)
#define NT1 8      // nodes per block in K1/K3
#define MIXW 640   // NP * FCH (w4 row stride)

__device__ __forceinline__ float silu(float x) { return x / (1.0f + __expf(-x)); }

constexpr float INV_SQRT128  = 0.08838834764831845f;
constexpr float INV_SQRT8    = 0.35355339059327373f;
constexpr float INV_64       = 0.125f;                 // 1/sqrt(64)
constexpr float INV_SQRT3    = 0.5773502691896258f;
constexpr float INV_SQRT2    = 0.7071067811865476f;
constexpr float INV_SQRT10   = 0.31622776601683794f;
constexpr float INV_SQRT1280 = 0.027950849718747374f;  // 1/sqrt(F*Z)
constexpr float INV_SQRT16   = 0.25f;
constexpr float EPSN         = 0.125f;

// ---------------------------------------------------------------- K1: node pre
__global__ __launch_bounds__(128) void k_node_pre(
    const float* __restrict__ ns, const float* __restrict__ nv,
    const float* __restrict__ w_skip, const float* __restrict__ w_up0,
    const float* __restrict__ w_up1, const int* __restrict__ species,
    float* __restrict__ hs, float* __restrict__ hv0, float* __restrict__ hv1,
    float* __restrict__ hv2, float* __restrict__ self_conn)
{
    __shared__ float ls[NT1][FCH];
    __shared__ float lv[3][NT1][FCH];
    __shared__ int lsp[NT1];
    const int g  = threadIdx.x;
    const int n0 = blockIdx.x * NT1;

    #pragma unroll
    for (int n = 0; n < NT1; ++n)
        ls[n][g] = ns[(size_t)(n0 + n) * FCH + g];
    for (int idx = g; idx < NT1 * FCH; idx += 128) {
        int n = idx >> 7, f = idx & 127;
        const float* src = nv + ((size_t)(n0 + n) * FCH + f) * 3;
        lv[0][n][f] = src[0];
        lv[1][n][f] = src[1];
        lv[2][n][f] = src[2];
    }
    if (g < NT1) lsp[g] = species[n0 + g];
    __syncthreads();

    const float* wk[NT1];
    #pragma unroll
    for (int n = 0; n < NT1; ++n)
        wk[n] = w_skip + (size_t)lsp[n] * FCH * FCH + g;

    float a_s[NT1], a0[NT1], a1[NT1], a2[NT1], a_k[NT1];
    #pragma unroll
    for (int n = 0; n < NT1; ++n) { a_s[n]=0; a0[n]=0; a1[n]=0; a2[n]=0; a_k[n]=0; }

    #pragma unroll 2
    for (int f = 0; f < FCH; ++f) {
        float u0 = w_up0[f * FCH + g];
        float u1 = w_up1[f * FCH + g];
        #pragma unroll
        for (int n = 0; n < NT1; ++n) {
            float s = ls[n][f];
            a_s[n] += s * u0;
            a0[n]  += lv[0][n][f] * u1;
            a1[n]  += lv[1][n][f] * u1;
            a2[n]  += lv[2][n][f] * u1;
            a_k[n] += s * wk[n][(size_t)f * FCH];
        }
    }
    #pragma unroll
    for (int n = 0; n < NT1; ++n) {
        size_t o = (size_t)(n0 + n) * FCH + g;
        hs[o]  = a_s[n] * INV_SQRT128;
        hv0[o] = a0[n]  * INV_SQRT128;
        hv1[o] = a1[n]  * INV_SQRT128;
        hv2[o] = a2[n]  * INV_SQRT128;
        self_conn[o] = a_k[n] * INV_SQRT1280;
    }
}

// ---------------------------------------------------------------- sort kernels
__global__ __launch_bounds__(256) void k_hist(
    const int* __restrict__ recv, int* __restrict__ counts)
{
    int e = blockIdx.x * 256 + threadIdx.x;
    atomicAdd(&counts[recv[e]], 1);
}

__global__ __launch_bounds__(1024) void k_scan(
    const int* __restrict__ counts, int* __restrict__ cursor)
{
    __shared__ int part[1024];
    const int t  = threadIdx.x;
    const int b0 = t * 32;
    int local[32];
    int s = 0;
    #pragma unroll
    for (int i = 0; i < 32; ++i) { local[i] = s; s += counts[b0 + i]; }
    part[t] = s;
    __syncthreads();
    for (int off = 1; off < 1024; off <<= 1) {
        int v   = part[t];
        int add = (t >= off) ? part[t - off] : 0;
        __syncthreads();
        part[t] = v + add;
        __syncthreads();
    }
    int base = (t == 0) ? 0 : part[t - 1];
    #pragma unroll
    for (int i = 0; i < 32; ++i) cursor[b0 + i] = base + local[i];
}

__global__ __launch_bounds__(256) void k_permute(
    const int* __restrict__ recv, int* __restrict__ cursor,
    int* __restrict__ perm)
{
    int e = blockIdx.x * 256 + threadIdx.x;
    int pos = atomicAdd(&cursor[recv[e]], 1);
    perm[pos] = e;
}

// ---------------------------------------------------------------- K2: fused
// Block = 64 receiver-sorted edges (exact). Radial MLP wave-private in-place
// in hA (no barriers between layers). Per path p: GEMM mx[8][4] against w4
// read straight from L2, then TP applied in two 4-edge subgroups with fresh
// es/ev gathers (L2-hit). Accumulate into 8-node LDS window keyed to the
// block's first receiver; overflow + flush go through global atomicAdd into
// zeroed agg arrays. 3 barriers per block, LDS 35.5KB -> 4 blocks/CU.
__global__ __launch_bounds__(256, 4) void k_edge(
    const float* __restrict__ vectors, const float* __restrict__ radial,
    const float* __restrict__ w1, const float* __restrict__ w2,
    const float* __restrict__ w3, const float* __restrict__ w4,
    const float* __restrict__ hs, const float* __restrict__ hv0,
    const float* __restrict__ hv1, const float* __restrict__ hv2,
    const int* __restrict__ senders, const int* __restrict__ receivers,
    const int* __restrict__ perm,
    float* __restrict__ agg_s, float* __restrict__ agg_v0,
    float* __restrict__ agg_v1, float* __restrict__ agg_v2)
{
    __shared__ __align__(16) float lrad[CE * NBASIS];  // 2KB
    __shared__ __align__(16) float hA[CE * HDIM];      // 16KB
    __shared__ float lY[CE][3];
    __shared__ int leid[CE], lsend[CE], lrecv[CE];
    __shared__ __align__(16) float laccS[8 * FCH];     // 4KB each
    __shared__ __align__(16) float laccV0[8 * FCH];
    __shared__ __align__(16) float laccV1[8 * FCH];
    __shared__ __align__(16) float laccV2[8 * FCH];

    const int tid = threadIdx.x;
    const int p0  = blockIdx.x * CE;

    if (tid < CE) {
        int eid = perm[p0 + tid];
        leid[tid]  = eid;
        lsend[tid] = senders[eid];
        lrecv[tid] = receivers[eid];
        float vx = vectors[(size_t)eid * 3 + 0];
        float vy = vectors[(size_t)eid * 3 + 1];
        float vz = vectors[(size_t)eid * 3 + 2];
        float rn = 1.0f / (sqrtf(vx*vx + vy*vy + vz*vz) + 1e-9f);
        lY[tid][0] = vx * rn; lY[tid][1] = vy * rn; lY[tid][2] = vz * rn;
    }
    for (int i = tid; i < 8 * FCH; i += 256) {
        laccS[i] = 0.f; laccV0[i] = 0.f; laccV1[i] = 0.f; laccV2[i] = 0.f;
    }
    __syncthreads();
    for (int idx = tid; idx < CE * NBASIS; idx += 256)
        lrad[idx] = radial[(size_t)leid[idx >> 3] * NBASIS + (idx & 7)];
    __syncthreads();   // barrier #2 (last before flush)

    // ---- radial MLP, wave-private rows [grp*16, +16), in-place in hA ----
    const int k    = tid & 63;
    const int grp  = tid >> 6;
    const int e_lo = grp * 16;
    {
        float w1c[NBASIS];
        #pragma unroll
        for (int j = 0; j < NBASIS; ++j) w1c[j] = w1[j * HDIM + k];
        for (int e = e_lo; e < e_lo + 16; ++e) {
            float acc = 0.f;
            #pragma unroll
            for (int j = 0; j < NBASIS; ++j) acc += lrad[e * NBASIS + j] * w1c[j];
            hA[e * HDIM + k] = silu(acc * INV_SQRT8);
        }
    }
    {
        float wc[HDIM];
        #pragma unroll
        for (int j = 0; j < HDIM; ++j) wc[j] = w2[j * HDIM + k];
        for (int e = e_lo; e < e_lo + 16; ++e) {
            float acc = 0.f;
            #pragma unroll
            for (int j = 0; j < HDIM; ++j) acc += hA[e * HDIM + j] * wc[j];
            hA[e * HDIM + k] = silu(acc * INV_64);
        }
    }
    {
        float wc[HDIM];
        #pragma unroll
        for (int j = 0; j < HDIM; ++j) wc[j] = w3[j * HDIM + k];
        for (int e = e_lo; e < e_lo + 16; ++e) {
            float acc = 0.f;
            #pragma unroll
            for (int j = 0; j < HDIM; ++j) acc += hA[e * HDIM + j] * wc[j];
            hA[e * HDIM + k] = silu(acc * INV_64);
        }
    }

    // ---- per-path GEMM (rows eb..eb+7, still wave-private) + TP ----
    const int fq  = (tid & 31) * 4;
    const int eg  = tid >> 5;
    const int eb  = eg * 8;
    const int rot = (tid >> 3) & 3;
    const int r0  = lrecv[0];
    const float* w4q = w4 + fq;

    #pragma unroll
    for (int p = 0; p < 5; ++p) {
        float mx[8][4];
        #pragma unroll
        for (int q = 0; q < 8; ++q) { mx[q][0]=0; mx[q][1]=0; mx[q][2]=0; mx[q][3]=0; }
        #pragma unroll 4
        for (int j = 0; j < HDIM; j += 4) {
            float4 wj0 = *(const float4*)(w4q + (size_t)(j+0)*MIXW + p*FCH);
            float4 wj1 = *(const float4*)(w4q + (size_t)(j+1)*MIXW + p*FCH);
            float4 wj2 = *(const float4*)(w4q + (size_t)(j+2)*MIXW + p*FCH);
            float4 wj3 = *(const float4*)(w4q + (size_t)(j+3)*MIXW + p*FCH);
            #pragma unroll
            for (int q = 0; q < 8; ++q) {
                float4 h4 = *(float4*)&hA[(eb + q) * HDIM + j];
                mx[q][0] += h4.x*wj0.x + h4.y*wj1.x + h4.z*wj2.x + h4.w*wj3.x;
                mx[q][1] += h4.x*wj0.y + h4.y*wj1.y + h4.z*wj2.y + h4.w*wj3.y;
                mx[q][2] += h4.x*wj0.z + h4.y*wj1.z + h4.z*wj2.z + h4.w*wj3.z;
                mx[q][3] += h4.x*wj0.w + h4.y*wj1.w + h4.z*wj2.w + h4.w*wj3.w;
            }
        }
        #pragma unroll
        for (int q = 0; q < 8; ++q) {
            mx[q][0] *= INV_64; mx[q][1] *= INV_64;
            mx[q][2] *= INV_64; mx[q][3] *= INV_64;
        }

        if (p == 0 || p == 2) {
            for (int sub = 0; sub < 2; ++sub) {
                const int e0 = eb + sub * 4;
                float es[4][4];
                #pragma unroll
                for (int q = 0; q < 4; ++q) {
                    float4 t = *(const float4*)(hs + (size_t)lsend[e0+q] * FCH + fq);
                    es[q][0]=t.x; es[q][1]=t.y; es[q][2]=t.z; es[q][3]=t.w;
                }
                #pragma unroll
                for (int q = 0; q < 4; ++q) {
                    const int e  = e0 + q;
                    const int mi = sub * 4 + q;
                    const int nl = lrecv[e] - r0;
                    if (p == 0) {
                        if (nl < 8) {
                            const int b = nl * FCH + fq;
                            #pragma unroll
                            for (int c = 0; c < 4; ++c) {
                                int cc = (c + rot) & 3;
                                atomicAdd(&laccS[b + cc], mx[mi][cc] * es[q][cc]);
                            }
                        } else {
                            const size_t go = (size_t)lrecv[e] * FCH + fq;
                            #pragma unroll
                            for (int c = 0; c < 4; ++c)
                                atomicAdd(&agg_s[go + c], mx[mi][c] * es[q][c]);
                        }
                    } else {
                        const float Yx = lY[e][0], Yy = lY[e][1], Yz = lY[e][2];
                        if (nl < 8) {
                            const int b = nl * FCH + fq;
                            #pragma unroll
                            for (int c = 0; c < 4; ++c) {
                                int cc = (c + rot) & 3;
                                float t = mx[mi][cc] * es[q][cc];
                                atomicAdd(&laccV0[b + cc], t * Yx);
                                atomicAdd(&laccV1[b + cc], t * Yy);
                                atomicAdd(&laccV2[b + cc], t * Yz);
                            }
                        } else {
                            const size_t go = (size_t)lrecv[e] * FCH + fq;
                            #pragma unroll
                            for (int c = 0; c < 4; ++c) {
                                float t = mx[mi][c] * es[q][c];
                                atomicAdd(&agg_v0[go + c], t * Yx);
                                atomicAdd(&agg_v1[go + c], t * Yy);
                                atomicAdd(&agg_v2[go + c], t * Yz);
                            }
                        }
                    }
                }
            }
        } else {
            for (int sub = 0; sub < 2; ++sub) {
                const int e0 = eb + sub * 4;
                float ev0[4][4], ev1[4][4], ev2[4][4];
                #pragma unroll
                for (int q = 0; q < 4; ++q) {
                    size_t o = (size_t)lsend[e0+q] * FCH + fq;
                    float4 t;
                    t = *(const float4*)(hv0 + o);
                    ev0[q][0]=t.x; ev0[q][1]=t.y; ev0[q][2]=t.z; ev0[q][3]=t.w;
                    t = *(const float4*)(hv1 + o);
                    ev1[q][0]=t.x; ev1[q][1]=t.y; ev1[q][2]=t.z; ev1[q][3]=t.w;
                    t = *(const float4*)(hv2 + o);
                    ev2[q][0]=t.x; ev2[q][1]=t.y; ev2[q][2]=t.z; ev2[q][3]=t.w;
                }
                #pragma unroll
                for (int q = 0; q < 4; ++q) {
                    const int e  = e0 + q;
                    const int mi = sub * 4 + q;
                    const int nl = lrecv[e] - r0;
                    const float Yx = lY[e][0], Yy = lY[e][1], Yz = lY[e][2];
                    if (p == 1) {
                        if (nl < 8) {
                            const int b = nl * FCH + fq;
                            #pragma unroll
                            for (int c = 0; c < 4; ++c) {
                                int cc = (c + rot) & 3;
                                float d = ev0[q][cc]*Yx + ev1[q][cc]*Yy + ev2[q][cc]*Yz;
                                atomicAdd(&laccS[b + cc], mx[mi][cc] * d * INV_SQRT3);
                            }
                        } else {
                            const size_t go = (size_t)lrecv[e] * FCH + fq;
                            #pragma unroll
                            for (int c = 0; c < 4; ++c) {
                                float d = ev0[q][c]*Yx + ev1[q][c]*Yy + ev2[q][c]*Yz;
                                atomicAdd(&agg_s[go + c], mx[mi][c] * d * INV_SQRT3);
                            }
                        }
                    } else if (p == 3) {
                        if (nl < 8) {
                            const int b = nl * FCH + fq;
                            #pragma unroll
                            for (int c = 0; c < 4; ++c) {
                                int cc = (c + rot) & 3;
                                float m = mx[mi][cc];
                                atomicAdd(&laccV0[b + cc], m * ev0[q][cc]);
                                atomicAdd(&laccV1[b + cc], m * ev1[q][cc]);
                                atomicAdd(&laccV2[b + cc], m * ev2[q][cc]);
                            }
                        } else {
                            const size_t go = (size_t)lrecv[e] * FCH + fq;
                            #pragma unroll
                            for (int c = 0; c < 4; ++c) {
                                float m = mx[mi][c];
                                atomicAdd(&agg_v0[go + c], m * ev0[q][c]);
                                atomicAdd(&agg_v1[go + c], m * ev1[q][c]);
                                atomicAdd(&agg_v2[go + c], m * ev2[q][c]);
                            }
                        }
                    } else {
                        if (nl < 8) {
                            const int b = nl * FCH + fq;
                            #pragma unroll
                            for (int c = 0; c < 4; ++c) {
                                int cc = (c + rot) & 3;
                                float m = mx[mi][cc] * INV_SQRT2;
                                float cx = ev1[q][cc]*Yz - ev2[q][cc]*Yy;
                                float cy = ev2[q][cc]*Yx - ev0[q][cc]*Yz;
                                float cz = ev0[q][cc]*Yy - ev1[q][cc]*Yx;
                                atomicAdd(&laccV0[b + cc], m * cx);
                                atomicAdd(&laccV1[b + cc], m * cy);
                                atomicAdd(&laccV2[b + cc], m * cz);
                            }
                        } else {
                            const size_t go = (size_t)lrecv[e] * FCH + fq;
                            #pragma unroll
                            for (int c = 0; c < 4; ++c) {
                                float m = mx[mi][c] * INV_SQRT2;
                                float cx = ev1[q][c]*Yz - ev2[q][c]*Yy;
                                float cy = ev2[q][c]*Yx - ev0[q][c]*Yz;
                                float cz = ev0[q][c]*Yy - ev1[q][c]*Yx;
                                atomicAdd(&agg_v0[go + c], m * cx);
                                atomicAdd(&agg_v1[go + c], m * cy);
                                atomicAdd(&agg_v2[go + c], m * cz);
                            }
                        }
                    }
                }
            }
        }
    } // p

    __syncthreads();   // barrier #3: window complete
    int span = lrecv[CE - 1] - r0;
    if (span > 7) span = 7;
    const int tot = (span + 1) * FCH;
    for (int i = tid; i < tot; i += 256) {
        const size_t go = (size_t)(r0 + (i >> 7)) * FCH + (i & 127);
        atomicAdd(&agg_s[go],  laccS[i]);
        atomicAdd(&agg_v0[go], laccV0[i]);
        atomicAdd(&agg_v1[go], laccV1[i]);
        atomicAdd(&agg_v2[go], laccV2[i]);
    }
}

// ---------------------------------------------------------------- K3: epilogue
__global__ __launch_bounds__(128) void k_epilogue(
    const float* __restrict__ agg_s, const float* __restrict__ agg_v0,
    const float* __restrict__ agg_v1, const float* __restrict__ agg_v2,
    const float* __restrict__ self_conn, const int* __restrict__ species,
    const float* __restrict__ w_down0, const float* __restrict__ w_down1,
    const float* __restrict__ w_sc, const float* __restrict__ w_post,
    const float* __restrict__ w_read1, const float* __restrict__ w_read2,
    float* __restrict__ out0, float* __restrict__ feats_out)
{
    __shared__ float lS[NT1][FCH];
    __shared__ float lV[3][NT1][FCH];
    __shared__ float fA[NT1][FCH];
    __shared__ float fB[NT1][FCH];
    __shared__ int lsp[NT1];
    const int g  = threadIdx.x;
    const int n0 = blockIdx.x * NT1;

    #pragma unroll
    for (int n = 0; n < NT1; ++n) {
        size_t o = (size_t)(n0 + n) * FCH + g;
        lS[n][g]    = agg_s[o]  * EPSN;
        lV[0][n][g] = agg_v0[o] * EPSN;
        lV[1][n][g] = agg_v1[o] * EPSN;
        lV[2][n][g] = agg_v2[o] * EPSN;
    }
    if (g < NT1) lsp[g] = species[n0 + g];
    __syncthreads();

    float xs[NT1], xv0[NT1], xv1[NT1], xv2[NT1];
    #pragma unroll
    for (int n = 0; n < NT1; ++n) { xs[n]=0; xv0[n]=0; xv1[n]=0; xv2[n]=0; }
    #pragma unroll 2
    for (int f = 0; f < FCH; ++f) {
        float d0 = w_down0[f * FCH + g];
        float d1 = w_down1[f * FCH + g];
        #pragma unroll
        for (int n = 0; n < NT1; ++n) {
            xs[n]  += lS[n][f] * d0;
            xv0[n] += lV[0][n][f] * d1;
            xv1[n] += lV[1][n][f] * d1;
            xv2[n] += lV[2][n][f] * d1;
        }
    }
    #pragma unroll
    for (int n = 0; n < NT1; ++n) {
        float s  = xs[n]  * INV_SQRT128;
        float v0 = xv0[n] * INV_SQRT128;
        float v1 = xv1[n] * INV_SQRT128;
        float v2 = xv2[n] * INV_SQRT128;
        int z = lsp[n];
        float wz0 = w_sc[((size_t)z * 3 + 0) * FCH + g] * INV_SQRT10;
        float wz1 = w_sc[((size_t)z * 3 + 1) * FCH + g] * INV_SQRT10;
        float wz2 = w_sc[((size_t)z * 3 + 2) * FCH + g] * INV_SQRT10;
        fA[n][g] = wz0 * s + wz1 * s * s + wz2 * (v0*v0 + v1*v1 + v2*v2);
    }
    __syncthreads();

    float fc[NT1];
    #pragma unroll
    for (int n = 0; n < NT1; ++n) fc[n] = 0;
    #pragma unroll 2
    for (int f = 0; f < FCH; ++f) {
        float wp = w_post[f * FCH + g];
        #pragma unroll
        for (int n = 0; n < NT1; ++n) fc[n] += fA[n][f] * wp;
    }
    #pragma unroll
    for (int n = 0; n < NT1; ++n) {
        size_t o = (size_t)(n0 + n) * FCH + g;
        float v = fc[n] * INV_SQRT128 + self_conn[o];
        fB[n][g] = v;
        feats_out[o] = v;
    }
    __syncthreads();

    const int n2 = g >> 4, r = g & 15;
    float acc = 0.f;
    for (int f = 0; f < FCH; ++f) acc += fB[n2][f] * w_read1[f * 16 + r];
    float t = silu(acc * INV_SQRT128);
    float val = t * w_read2[r];
    val += __shfl_down(val, 8, 16);
    val += __shfl_down(val, 4, 16);
    val += __shfl_down(val, 2, 16);
    val += __shfl_down(val, 1, 16);
    if (r == 0) out0[n0 + n2] = val * INV_SQRT16;
}

// ---------------------------------------------------------------- launch
extern "C" void kernel_launch(void* const* d_in, const int* in_sizes, int n_in,
                              void* d_out, int out_size, void* d_ws, size_t ws_size,
                              hipStream_t stream) {
    (void)in_sizes; (void)n_in; (void)out_size; (void)ws_size;
    const float* vectors      = (const float*)d_in[0];
    const float* node_scalars = (const float*)d_in[1];
    const float* node_vectors = (const float*)d_in[2];
    const float* radial       = (const float*)d_in[3];
    const float* w_skip       = (const float*)d_in[4];
    const float* w_up0        = (const float*)d_in[5];
    const float* w_up1        = (const float*)d_in[6];
    const float* mlp_w1       = (const float*)d_in[7];
    const float* mlp_w2       = (const float*)d_in[8];
    const float* mlp_w3       = (const float*)d_in[9];
    const float* mlp_w4       = (const float*)d_in[10];
    const float* w_down0      = (const float*)d_in[11];
    const float* w_down1      = (const float*)d_in[12];
    const float* w_sc         = (const float*)d_in[13];
    const float* w_post       = (const float*)d_in[14];
    const float* w_read1      = (const float*)d_in[15];
    const float* w_read2      = (const float*)d_in[16];
    const int*   senders      = (const int*)d_in[17];
    const int*   receivers    = (const int*)d_in[18];
    const int*   species      = (const int*)d_in[19];

    const size_t NF = (size_t)N_NODES * FCH;
    float* ws     = (float*)d_ws;
    float* hs     = ws;
    float* hv0    = ws + 1 * NF;
    float* hv1    = ws + 2 * NF;
    float* hv2    = ws + 3 * NF;
    float* agg_s  = ws + 4 * NF;
    float* agg_v0 = ws + 5 * NF;
    float* agg_v1 = ws + 6 * NF;
    float* agg_v2 = ws + 7 * NF;
    int* counts   = (int*)(ws + 8 * NF);      // [N]
    int* cursor   = counts + N_NODES;         // [N]
    int* perm     = cursor + N_NODES;         // [E]

    float* out       = (float*)d_out;
    float* feats     = out + N_NODES;   // final feats output
    float* self_conn = feats;           // scratch until epilogue overwrites

    hipMemsetAsync(counts, 0, N_NODES * sizeof(int), stream);
    hipMemsetAsync(agg_s, 0, 4 * NF * sizeof(float), stream);

    k_node_pre<<<N_NODES / NT1, 128, 0, stream>>>(
        node_scalars, node_vectors, w_skip, w_up0, w_up1, species,
        hs, hv0, hv1, hv2, self_conn);

    k_hist<<<N_EDGES / 256, 256, 0, stream>>>(receivers, counts);
    k_scan<<<1, 1024, 0, stream>>>(counts, cursor);
    k_permute<<<N_EDGES / 256, 256, 0, stream>>>(receivers, cursor, perm);

    k_edge<<<N_EDGES / CE, 256, 0, stream>>>(
        vectors, radial, mlp_w1, mlp_w2, mlp_w3, mlp_w4,
        hs, hv0, hv1, hv2, senders, receivers, perm,
        agg_s, agg_v0, agg_v1, agg_v2);

    k_epilogue<<<N_NODES / NT1, 128, 0, stream>>>(
        agg_s, agg_v0, agg_v1, agg_v2, self_conn, species,
        w_down0, w_down1, w_sc, w_post, w_read1, w_read2,
        out, feats);
}

// Round 3
// 3905.230 us; speedup vs baseline: 1.2776x; 1.2776x over previous
//
#include <hip/hip_runtime.h>
#include <math.h>

// MACE layer, f32. Round 9: R8 fused kernel regressed (4625us, VALU 20%,
// WRITE 4.36GB, VGPR_Count=64) -> massive scratch spills: wc[64] per-thread
// weight arrays + RUNTIME-indexed register arrays (mx[mi][(c+rot)&3]) forced
// scratch allocation at the 64-VGPR tier. Fix: (1) drop rot (dynamic index)
// entirely -- 2-way LDS atomic conflicts are free; (2) MLP layers 2/3 as
// j-outer with acc[16] accumulators (no wc[64]); (3) operand-grouped paths:
// one 8-edge GEMM for {p0,p2} then es gathered ONCE/edge; two 4-edge GEMMs
// for {p1,p3,p4} then ev gathered ONCE/edge, p3+p4 merged into one atomic.
// Gathers 5.6KB -> 2KB/edge. Peak live ~95 VGPR, launch_bounds(256,2).
// K1: node pre   Ksort: hist/scan/permute   K2: fused edge   K3: epilogue

#define N_NODES 32768
#define N_EDGES 524288
#define FCH 128
#define NBASIS 8
#define HDIM 64
#define CE 64      // edges per block in K2 (N_EDGES = 8192 * CE exactly)
#define NT1 8      // nodes per block in K1/K3
#define MIXW 640   // NP * FCH (w4 row stride)

__device__ __forceinline__ float silu(float x) { return x / (1.0f + __expf(-x)); }

constexpr float INV_SQRT128  = 0.08838834764831845f;
constexpr float INV_SQRT8    = 0.35355339059327373f;
constexpr float INV_64       = 0.125f;                 // 1/sqrt(64)
constexpr float INV_SQRT3    = 0.5773502691896258f;
constexpr float INV_SQRT2    = 0.7071067811865476f;
constexpr float INV_SQRT10   = 0.31622776601683794f;
constexpr float INV_SQRT1280 = 0.027950849718747374f;  // 1/sqrt(F*Z)
constexpr float INV_SQRT16   = 0.25f;
constexpr float EPSN         = 0.125f;
constexpr float C_P1         = 0.07216878364870323f;   // INV_SQRT3 * INV_64
constexpr float C_P4         = 0.08838834764831845f;   // INV_SQRT2 * INV_64

// ---------------------------------------------------------------- K1: node pre
__global__ __launch_bounds__(128) void k_node_pre(
    const float* __restrict__ ns, const float* __restrict__ nv,
    const float* __restrict__ w_skip, const float* __restrict__ w_up0,
    const float* __restrict__ w_up1, const int* __restrict__ species,
    float* __restrict__ hs, float* __restrict__ hv0, float* __restrict__ hv1,
    float* __restrict__ hv2, float* __restrict__ self_conn)
{
    __shared__ float ls[NT1][FCH];
    __shared__ float lv[3][NT1][FCH];
    __shared__ int lsp[NT1];
    const int g  = threadIdx.x;
    const int n0 = blockIdx.x * NT1;

    #pragma unroll
    for (int n = 0; n < NT1; ++n)
        ls[n][g] = ns[(size_t)(n0 + n) * FCH + g];
    for (int idx = g; idx < NT1 * FCH; idx += 128) {
        int n = idx >> 7, f = idx & 127;
        const float* src = nv + ((size_t)(n0 + n) * FCH + f) * 3;
        lv[0][n][f] = src[0];
        lv[1][n][f] = src[1];
        lv[2][n][f] = src[2];
    }
    if (g < NT1) lsp[g] = species[n0 + g];
    __syncthreads();

    const float* wk[NT1];
    #pragma unroll
    for (int n = 0; n < NT1; ++n)
        wk[n] = w_skip + (size_t)lsp[n] * FCH * FCH + g;

    float a_s[NT1], a0[NT1], a1[NT1], a2[NT1], a_k[NT1];
    #pragma unroll
    for (int n = 0; n < NT1; ++n) { a_s[n]=0; a0[n]=0; a1[n]=0; a2[n]=0; a_k[n]=0; }

    #pragma unroll 2
    for (int f = 0; f < FCH; ++f) {
        float u0 = w_up0[f * FCH + g];
        float u1 = w_up1[f * FCH + g];
        #pragma unroll
        for (int n = 0; n < NT1; ++n) {
            float s = ls[n][f];
            a_s[n] += s * u0;
            a0[n]  += lv[0][n][f] * u1;
            a1[n]  += lv[1][n][f] * u1;
            a2[n]  += lv[2][n][f] * u1;
            a_k[n] += s * wk[n][(size_t)f * FCH];
        }
    }
    #pragma unroll
    for (int n = 0; n < NT1; ++n) {
        size_t o = (size_t)(n0 + n) * FCH + g;
        hs[o]  = a_s[n] * INV_SQRT128;
        hv0[o] = a0[n]  * INV_SQRT128;
        hv1[o] = a1[n]  * INV_SQRT128;
        hv2[o] = a2[n]  * INV_SQRT128;
        self_conn[o] = a_k[n] * INV_SQRT1280;
    }
}

// ---------------------------------------------------------------- sort kernels
__global__ __launch_bounds__(256) void k_hist(
    const int* __restrict__ recv, int* __restrict__ counts)
{
    int e = blockIdx.x * 256 + threadIdx.x;
    atomicAdd(&counts[recv[e]], 1);
}

__global__ __launch_bounds__(1024) void k_scan(
    const int* __restrict__ counts, int* __restrict__ cursor)
{
    __shared__ int part[1024];
    const int t  = threadIdx.x;
    const int b0 = t * 32;
    int local[32];
    int s = 0;
    #pragma unroll
    for (int i = 0; i < 32; ++i) { local[i] = s; s += counts[b0 + i]; }
    part[t] = s;
    __syncthreads();
    for (int off = 1; off < 1024; off <<= 1) {
        int v   = part[t];
        int add = (t >= off) ? part[t - off] : 0;
        __syncthreads();
        part[t] = v + add;
        __syncthreads();
    }
    int base = (t == 0) ? 0 : part[t - 1];
    #pragma unroll
    for (int i = 0; i < 32; ++i) cursor[b0 + i] = base + local[i];
}

__global__ __launch_bounds__(256) void k_permute(
    const int* __restrict__ recv, int* __restrict__ cursor,
    int* __restrict__ perm)
{
    int e = blockIdx.x * 256 + threadIdx.x;
    int pos = atomicAdd(&cursor[recv[e]], 1);
    perm[pos] = e;
}

// ---------------------------------------------------------------- K2: fused
// Block = 64 receiver-sorted edges. MLP wave-private in hA (acc-register
// j-outer form, no big per-thread arrays). Path GEMMs grouped by operand so
// es is gathered once/edge (p0,p2) and ev once/edge (p1,p3,p4; p3+p4 merged
// into one atomic per component). No runtime-indexed register arrays.
__global__ __launch_bounds__(256, 2) void k_edge(
    const float* __restrict__ vectors, const float* __restrict__ radial,
    const float* __restrict__ w1, const float* __restrict__ w2,
    const float* __restrict__ w3, const float* __restrict__ w4,
    const float* __restrict__ hs, const float* __restrict__ hv0,
    const float* __restrict__ hv1, const float* __restrict__ hv2,
    const int* __restrict__ senders, const int* __restrict__ receivers,
    const int* __restrict__ perm,
    float* __restrict__ agg_s, float* __restrict__ agg_v0,
    float* __restrict__ agg_v1, float* __restrict__ agg_v2)
{
    __shared__ __align__(16) float lrad[CE * NBASIS];  // 2KB
    __shared__ __align__(16) float hA[CE * HDIM];      // 16KB
    __shared__ float lY[CE][3];
    __shared__ int leid[CE], lsend[CE], lrecv[CE];
    __shared__ __align__(16) float laccS[8 * FCH];     // 4KB each
    __shared__ __align__(16) float laccV0[8 * FCH];
    __shared__ __align__(16) float laccV1[8 * FCH];
    __shared__ __align__(16) float laccV2[8 * FCH];

    const int tid = threadIdx.x;
    const int p0  = blockIdx.x * CE;

    if (tid < CE) {
        int eid = perm[p0 + tid];
        leid[tid]  = eid;
        lsend[tid] = senders[eid];
        lrecv[tid] = receivers[eid];
        float vx = vectors[(size_t)eid * 3 + 0];
        float vy = vectors[(size_t)eid * 3 + 1];
        float vz = vectors[(size_t)eid * 3 + 2];
        float rn = 1.0f / (sqrtf(vx*vx + vy*vy + vz*vz) + 1e-9f);
        lY[tid][0] = vx * rn; lY[tid][1] = vy * rn; lY[tid][2] = vz * rn;
    }
    for (int i = tid; i < 8 * FCH; i += 256) {
        laccS[i] = 0.f; laccV0[i] = 0.f; laccV1[i] = 0.f; laccV2[i] = 0.f;
    }
    __syncthreads();
    for (int idx = tid; idx < CE * NBASIS; idx += 256)
        lrad[idx] = radial[(size_t)leid[idx >> 3] * NBASIS + (idx & 7)];
    __syncthreads();   // barrier #2 (last before flush)

    // ---- radial MLP, wave-private rows [grp*16, +16) ----
    const int k    = tid & 63;
    const int grp  = tid >> 6;
    const int e_lo = grp * 16;

    {   // layer 1 (8->64), direct per-row
        float w1c[NBASIS];
        #pragma unroll
        for (int j = 0; j < NBASIS; ++j) w1c[j] = w1[j * HDIM + k];
        #pragma unroll 4
        for (int e = 0; e < 16; ++e) {
            const float* r = &lrad[(e_lo + e) * NBASIS];
            float a = r[0]*w1c[0] + r[1]*w1c[1] + r[2]*w1c[2] + r[3]*w1c[3]
                    + r[4]*w1c[4] + r[5]*w1c[5] + r[6]*w1c[6] + r[7]*w1c[7];
            hA[(e_lo + e) * HDIM + k] = silu(a * INV_SQRT8);
        }
    }
    {   // layer 2 (64->64): j-outer, acc[16]; read all rows before writing
        float acc[16];
        #pragma unroll
        for (int e = 0; e < 16; ++e) acc[e] = 0.f;
        #pragma unroll 2
        for (int j = 0; j < HDIM; j += 4) {
            float wa = w2[(j+0) * HDIM + k];
            float wb = w2[(j+1) * HDIM + k];
            float wc = w2[(j+2) * HDIM + k];
            float wd = w2[(j+3) * HDIM + k];
            #pragma unroll
            for (int e = 0; e < 16; ++e) {
                float4 h = *(float4*)&hA[(e_lo + e) * HDIM + j];
                acc[e] += h.x*wa + h.y*wb + h.z*wc + h.w*wd;
            }
        }
        #pragma unroll
        for (int e = 0; e < 16; ++e)
            hA[(e_lo + e) * HDIM + k] = silu(acc[e] * INV_64);
    }
    {   // layer 3 (64->64)
        float acc[16];
        #pragma unroll
        for (int e = 0; e < 16; ++e) acc[e] = 0.f;
        #pragma unroll 2
        for (int j = 0; j < HDIM; j += 4) {
            float wa = w3[(j+0) * HDIM + k];
            float wb = w3[(j+1) * HDIM + k];
            float wc = w3[(j+2) * HDIM + k];
            float wd = w3[(j+3) * HDIM + k];
            #pragma unroll
            for (int e = 0; e < 16; ++e) {
                float4 h = *(float4*)&hA[(e_lo + e) * HDIM + j];
                acc[e] += h.x*wa + h.y*wb + h.z*wc + h.w*wd;
            }
        }
        #pragma unroll
        for (int e = 0; e < 16; ++e)
            hA[(e_lo + e) * HDIM + k] = silu(acc[e] * INV_64);
    }

    // ---- operand-grouped path GEMMs + TP ----
    const int fq = (tid & 31) * 4;
    const int eg = tid >> 5;
    const int eb = eg * 8;
    const int r0 = lrecv[0];
    const float* w4q = w4 + fq;

    // ===== es-group: paths 0 and 2 over 8 edges, es gathered once/edge =====
    {
        float ma[8][4], mc[8][4];
        #pragma unroll
        for (int q = 0; q < 8; ++q)
            #pragma unroll
            for (int c = 0; c < 4; ++c) { ma[q][c] = 0.f; mc[q][c] = 0.f; }
        #pragma unroll 2
        for (int j = 0; j < HDIM; j += 2) {
            float4 w0a = *(const float4*)(w4q + (size_t)(j+0) * MIXW);
            float4 w0b = *(const float4*)(w4q + (size_t)(j+1) * MIXW);
            float4 w2a = *(const float4*)(w4q + (size_t)(j+0) * MIXW + 2*FCH);
            float4 w2b = *(const float4*)(w4q + (size_t)(j+1) * MIXW + 2*FCH);
            #pragma unroll
            for (int q = 0; q < 8; ++q) {
                float2 h = *(float2*)&hA[(eb + q) * HDIM + j];
                ma[q][0] += h.x*w0a.x + h.y*w0b.x;
                ma[q][1] += h.x*w0a.y + h.y*w0b.y;
                ma[q][2] += h.x*w0a.z + h.y*w0b.z;
                ma[q][3] += h.x*w0a.w + h.y*w0b.w;
                mc[q][0] += h.x*w2a.x + h.y*w2b.x;
                mc[q][1] += h.x*w2a.y + h.y*w2b.y;
                mc[q][2] += h.x*w2a.z + h.y*w2b.z;
                mc[q][3] += h.x*w2a.w + h.y*w2b.w;
            }
        }
        #pragma unroll
        for (int q = 0; q < 8; ++q) {
            const int e  = eb + q;
            const int nl = lrecv[e] - r0;
            float4 t4 = *(const float4*)(hs + (size_t)lsend[e] * FCH + fq);
            float es[4] = { t4.x, t4.y, t4.z, t4.w };
            const float Yx = lY[e][0], Yy = lY[e][1], Yz = lY[e][2];
            if (nl < 8) {
                const int b = nl * FCH + fq;
                #pragma unroll
                for (int c = 0; c < 4; ++c) {
                    float s = ma[q][c] * es[c] * INV_64;
                    float t = mc[q][c] * es[c] * INV_64;
                    atomicAdd(&laccS[b + c],  s);
                    atomicAdd(&laccV0[b + c], t * Yx);
                    atomicAdd(&laccV1[b + c], t * Yy);
                    atomicAdd(&laccV2[b + c], t * Yz);
                }
            } else {
                const size_t go = (size_t)lrecv[e] * FCH + fq;
                #pragma unroll
                for (int c = 0; c < 4; ++c) {
                    float s = ma[q][c] * es[c] * INV_64;
                    float t = mc[q][c] * es[c] * INV_64;
                    atomicAdd(&agg_s[go + c],  s);
                    atomicAdd(&agg_v0[go + c], t * Yx);
                    atomicAdd(&agg_v1[go + c], t * Yy);
                    atomicAdd(&agg_v2[go + c], t * Yz);
                }
            }
        }
    }

    // ===== ev-group: paths 1,3,4 over two 4-edge halves, ev once/edge =====
    #pragma unroll
    for (int half = 0; half < 2; ++half) {
        const int e0 = eb + half * 4;
        float m1[4][4], m3[4][4], m5[4][4];
        #pragma unroll
        for (int q = 0; q < 4; ++q)
            #pragma unroll
            for (int c = 0; c < 4; ++c) { m1[q][c]=0.f; m3[q][c]=0.f; m5[q][c]=0.f; }
        #pragma unroll 2
        for (int j = 0; j < HDIM; j += 2) {
            float4 wa1 = *(const float4*)(w4q + (size_t)(j+0) * MIXW + 1*FCH);
            float4 wb1 = *(const float4*)(w4q + (size_t)(j+1) * MIXW + 1*FCH);
            float4 wa3 = *(const float4*)(w4q + (size_t)(j+0) * MIXW + 3*FCH);
            float4 wb3 = *(const float4*)(w4q + (size_t)(j+1) * MIXW + 3*FCH);
            float4 wa4 = *(const float4*)(w4q + (size_t)(j+0) * MIXW + 4*FCH);
            float4 wb4 = *(const float4*)(w4q + (size_t)(j+1) * MIXW + 4*FCH);
            #pragma unroll
            for (int q = 0; q < 4; ++q) {
                float2 h = *(float2*)&hA[(e0 + q) * HDIM + j];
                m1[q][0] += h.x*wa1.x + h.y*wb1.x;
                m1[q][1] += h.x*wa1.y + h.y*wb1.y;
                m1[q][2] += h.x*wa1.z + h.y*wb1.z;
                m1[q][3] += h.x*wa1.w + h.y*wb1.w;
                m3[q][0] += h.x*wa3.x + h.y*wb3.x;
                m3[q][1] += h.x*wa3.y + h.y*wb3.y;
                m3[q][2] += h.x*wa3.z + h.y*wb3.z;
                m3[q][3] += h.x*wa3.w + h.y*wb3.w;
                m5[q][0] += h.x*wa4.x + h.y*wb4.x;
                m5[q][1] += h.x*wa4.y + h.y*wb4.y;
                m5[q][2] += h.x*wa4.z + h.y*wb4.z;
                m5[q][3] += h.x*wa4.w + h.y*wb4.w;
            }
        }
        #pragma unroll
        for (int q = 0; q < 4; ++q) {
            const int e  = e0 + q;
            const int nl = lrecv[e] - r0;
            const size_t so = (size_t)lsend[e] * FCH + fq;
            float4 t0 = *(const float4*)(hv0 + so);
            float4 t1 = *(const float4*)(hv1 + so);
            float4 t2 = *(const float4*)(hv2 + so);
            float ev0[4] = { t0.x, t0.y, t0.z, t0.w };
            float ev1[4] = { t1.x, t1.y, t1.z, t1.w };
            float ev2[4] = { t2.x, t2.y, t2.z, t2.w };
            const float Yx = lY[e][0], Yy = lY[e][1], Yz = lY[e][2];
            if (nl < 8) {
                const int b = nl * FCH + fq;
                #pragma unroll
                for (int c = 0; c < 4; ++c) {
                    float d  = ev0[c]*Yx + ev1[c]*Yy + ev2[c]*Yz;
                    float sv = m1[q][c] * d * C_P1;
                    float m3v = m3[q][c] * INV_64;
                    float m4v = m5[q][c] * C_P4;
                    float v0 = m3v*ev0[c] + m4v*(ev1[c]*Yz - ev2[c]*Yy);
                    float v1 = m3v*ev1[c] + m4v*(ev2[c]*Yx - ev0[c]*Yz);
                    float v2 = m3v*ev2[c] + m4v*(ev0[c]*Yy - ev1[c]*Yx);
                    atomicAdd(&laccS[b + c],  sv);
                    atomicAdd(&laccV0[b + c], v0);
                    atomicAdd(&laccV1[b + c], v1);
                    atomicAdd(&laccV2[b + c], v2);
                }
            } else {
                const size_t go = (size_t)lrecv[e] * FCH + fq;
                #pragma unroll
                for (int c = 0; c < 4; ++c) {
                    float d  = ev0[c]*Yx + ev1[c]*Yy + ev2[c]*Yz;
                    float sv = m1[q][c] * d * C_P1;
                    float m3v = m3[q][c] * INV_64;
                    float m4v = m5[q][c] * C_P4;
                    float v0 = m3v*ev0[c] + m4v*(ev1[c]*Yz - ev2[c]*Yy);
                    float v1 = m3v*ev1[c] + m4v*(ev2[c]*Yx - ev0[c]*Yz);
                    float v2 = m3v*ev2[c] + m4v*(ev0[c]*Yy - ev1[c]*Yx);
                    atomicAdd(&agg_s[go + c],  sv);
                    atomicAdd(&agg_v0[go + c], v0);
                    atomicAdd(&agg_v1[go + c], v1);
                    atomicAdd(&agg_v2[go + c], v2);
                }
            }
        }
    }

    __syncthreads();   // barrier #3: window complete
    int span = lrecv[CE - 1] - r0;
    if (span > 7) span = 7;
    const int tot = (span + 1) * FCH;
    for (int i = tid; i < tot; i += 256) {
        const size_t go = (size_t)(r0 + (i >> 7)) * FCH + (i & 127);
        atomicAdd(&agg_s[go],  laccS[i]);
        atomicAdd(&agg_v0[go], laccV0[i]);
        atomicAdd(&agg_v1[go], laccV1[i]);
        atomicAdd(&agg_v2[go], laccV2[i]);
    }
}

// ---------------------------------------------------------------- K3: epilogue
__global__ __launch_bounds__(128) void k_epilogue(
    const float* __restrict__ agg_s, const float* __restrict__ agg_v0,
    const float* __restrict__ agg_v1, const float* __restrict__ agg_v2,
    const float* __restrict__ self_conn, const int* __restrict__ species,
    const float* __restrict__ w_down0, const float* __restrict__ w_down1,
    const float* __restrict__ w_sc, const float* __restrict__ w_post,
    const float* __restrict__ w_read1, const float* __restrict__ w_read2,
    float* __restrict__ out0, float* __restrict__ feats_out)
{
    __shared__ float lS[NT1][FCH];
    __shared__ float lV[3][NT1][FCH];
    __shared__ float fA[NT1][FCH];
    __shared__ float fB[NT1][FCH];
    __shared__ int lsp[NT1];
    const int g  = threadIdx.x;
    const int n0 = blockIdx.x * NT1;

    #pragma unroll
    for (int n = 0; n < NT1; ++n) {
        size_t o = (size_t)(n0 + n) * FCH + g;
        lS[n][g]    = agg_s[o]  * EPSN;
        lV[0][n][g] = agg_v0[o] * EPSN;
        lV[1][n][g] = agg_v1[o] * EPSN;
        lV[2][n][g] = agg_v2[o] * EPSN;
    }
    if (g < NT1) lsp[g] = species[n0 + g];
    __syncthreads();

    float xs[NT1], xv0[NT1], xv1[NT1], xv2[NT1];
    #pragma unroll
    for (int n = 0; n < NT1; ++n) { xs[n]=0; xv0[n]=0; xv1[n]=0; xv2[n]=0; }
    #pragma unroll 2
    for (int f = 0; f < FCH; ++f) {
        float d0 = w_down0[f * FCH + g];
        float d1 = w_down1[f * FCH + g];
        #pragma unroll
        for (int n = 0; n < NT1; ++n) {
            xs[n]  += lS[n][f] * d0;
            xv0[n] += lV[0][n][f] * d1;
            xv1[n] += lV[1][n][f] * d1;
            xv2[n] += lV[2][n][f] * d1;
        }
    }
    #pragma unroll
    for (int n = 0; n < NT1; ++n) {
        float s  = xs[n]  * INV_SQRT128;
        float v0 = xv0[n] * INV_SQRT128;
        float v1 = xv1[n] * INV_SQRT128;
        float v2 = xv2[n] * INV_SQRT128;
        int z = lsp[n];
        float wz0 = w_sc[((size_t)z * 3 + 0) * FCH + g] * INV_SQRT10;
        float wz1 = w_sc[((size_t)z * 3 + 1) * FCH + g] * INV_SQRT10;
        float wz2 = w_sc[((size_t)z * 3 + 2) * FCH + g] * INV_SQRT10;
        fA[n][g] = wz0 * s + wz1 * s * s + wz2 * (v0*v0 + v1*v1 + v2*v2);
    }
    __syncthreads();

    float fc[NT1];
    #pragma unroll
    for (int n = 0; n < NT1; ++n) fc[n] = 0;
    #pragma unroll 2
    for (int f = 0; f < FCH; ++f) {
        float wp = w_post[f * FCH + g];
        #pragma unroll
        for (int n = 0; n < NT1; ++n) fc[n] += fA[n][f] * wp;
    }
    #pragma unroll
    for (int n = 0; n < NT1; ++n) {
        size_t o = (size_t)(n0 + n) * FCH + g;
        float v = fc[n] * INV_SQRT128 + self_conn[o];
        fB[n][g] = v;
        feats_out[o] = v;
    }
    __syncthreads();

    const int n2 = g >> 4, r = g & 15;
    float acc = 0.f;
    for (int f = 0; f < FCH; ++f) acc += fB[n2][f] * w_read1[f * 16 + r];
    float t = silu(acc * INV_SQRT128);
    float val = t * w_read2[r];
    val += __shfl_down(val, 8, 16);
    val += __shfl_down(val, 4, 16);
    val += __shfl_down(val, 2, 16);
    val += __shfl_down(val, 1, 16);
    if (r == 0) out0[n0 + n2] = val * INV_SQRT16;
}

// ---------------------------------------------------------------- launch
extern "C" void kernel_launch(void* const* d_in, const int* in_sizes, int n_in,
                              void* d_out, int out_size, void* d_ws, size_t ws_size,
                              hipStream_t stream) {
    (void)in_sizes; (void)n_in; (void)out_size; (void)ws_size;
    const float* vectors      = (const float*)d_in[0];
    const float* node_scalars = (const float*)d_in[1];
    const float* node_vectors = (const float*)d_in[2];
    const float* radial       = (const float*)d_in[3];
    const float* w_skip       = (const float*)d_in[4];
    const float* w_up0        = (const float*)d_in[5];
    const float* w_up1        = (const float*)d_in[6];
    const float* mlp_w1       = (const float*)d_in[7];
    const float* mlp_w2       = (const float*)d_in[8];
    const float* mlp_w3       = (const float*)d_in[9];
    const float* mlp_w4       = (const float*)d_in[10];
    const float* w_down0      = (const float*)d_in[11];
    const float* w_down1      = (const float*)d_in[12];
    const float* w_sc         = (const float*)d_in[13];
    const float* w_post       = (const float*)d_in[14];
    const float* w_read1      = (const float*)d_in[15];
    const float* w_read2      = (const float*)d_in[16];
    const int*   senders      = (const int*)d_in[17];
    const int*   receivers    = (const int*)d_in[18];
    const int*   species      = (const int*)d_in[19];

    const size_t NF = (size_t)N_NODES * FCH;
    float* ws     = (float*)d_ws;
    float* hs     = ws;
    float* hv0    = ws + 1 * NF;
    float* hv1    = ws + 2 * NF;
    float* hv2    = ws + 3 * NF;
    float* agg_s  = ws + 4 * NF;
    float* agg_v0 = ws + 5 * NF;
    float* agg_v1 = ws + 6 * NF;
    float* agg_v2 = ws + 7 * NF;
    int* counts   = (int*)(ws + 8 * NF);      // [N]
    int* cursor   = counts + N_NODES;         // [N]
    int* perm     = cursor + N_NODES;         // [E]

    float* out       = (float*)d_out;
    float* feats     = out + N_NODES;   // final feats output
    float* self_conn = feats;           // scratch until epilogue overwrites

    hipMemsetAsync(counts, 0, N_NODES * sizeof(int), stream);
    hipMemsetAsync(agg_s, 0, 4 * NF * sizeof(float), stream);

    k_node_pre<<<N_NODES / NT1, 128, 0, stream>>>(
        node_scalars, node_vectors, w_skip, w_up0, w_up1, species,
        hs, hv0, hv1, hv2, self_conn);

    k_hist<<<N_EDGES / 256, 256, 0, stream>>>(receivers, counts);
    k_scan<<<1, 1024, 0, stream>>>(counts, cursor);
    k_permute<<<N_EDGES / 256, 256, 0, stream>>>(receivers, cursor, perm);

    k_edge<<<N_EDGES / CE, 256, 0, stream>>>(
        vectors, radial, mlp_w1, mlp_w2, mlp_w3, mlp_w4,
        hs, hv0, hv1, hv2, senders, receivers, perm,
        agg_s, agg_v0, agg_v1, agg_v2);

    k_epilogue<<<N_NODES / NT1, 128, 0, stream>>>(
        agg_s, agg_v0, agg_v1, agg_v2, self_conn, species,
        w_down0, w_down1, w_sc, w_post, w_read1, w_read2,
        out, feats);
}